// Round 7
// baseline (346.070 us; speedup 1.0000x reference)
//
#include <hip/hip_runtime.h>
#include <math.h>

// ---------------------------------------------------------------------------
// GCN 2-layer forward. ELL adjacency built with ZERO device-scope atomics:
//   K1 k_prep_hist : [prep blocks: wt, dummy rows] ++ [edge histogram]
//   K2 k_colsum    : 196 blocks: per-bucket local prefix over edge-blocks
//                    (replaces the single-block k_scan; bstart recomputed
//                    in-block from bcount by bin/ell — concurrent, free)
//   K3 k_bin_gemm  : [bin blocks: packed (src,dstLow)] ++ [gemm blocks: MFMA
//                    h' = x @ W1, bf16, UNSCALED -> no deg dependency]
//   K4 k_ell       : one block per bucket: LDS counting sort -> coalesced
//                    int4 col writes; writes deg[] and dinv[]
//   K5 k_gather1f  : gather h*dinv[src] + relu + (128->16 matvec) -> g [fp16]
//   K6 k_gather2   : gather g, 2 lanes/node f16x8 (16B) loads (halves L2
//                    request count) + bias + log_softmax
// r0-r6 findings: gather1f pinned at ~125-131us / ~192-198MB FETCH / 1.6 TB/s
// across 6 schedules -> L2<->LLC fabric floor for random 256B rows; closed.
// SW pipelining null (r1); nt scatter + global deg atomics regress (r3);
// fp16 g ok (r4); bin+gemm fusion ok (r5); counting-sort ell +3.6us (r6).
// This rev targets the ~214us non-gather1f残: single-block scan latency and
// gather2's L2 request rate.
// ---------------------------------------------------------------------------

#define ELLW 72       // multiple of 8 (deg~Poisson(16); no clamp in practice)
#define EPB 16384     // edges per hist/bin block
#define BSH 9         // bucket = 512 nodes
#define MAXEB 100     // >= ceil(E/EPB) = 98
#define MAXBK 200     // >= ceil(n/512) = 196
#define SORTCAP 10240 // LDS sorted-edge capacity (avg bucket 8163, 23 sigma)

typedef __attribute__((ext_vector_type(8))) short short8;
typedef __attribute__((ext_vector_type(4))) float f32x4;
typedef __attribute__((ext_vector_type(4))) int i32x4;
typedef __attribute__((ext_vector_type(4))) _Float16 f16x4;
typedef __attribute__((ext_vector_type(8))) _Float16 f16x8;

__device__ __forceinline__ float bf2f(unsigned short u) {
    return __uint_as_float(((unsigned int)u) << 16);
}
__device__ __forceinline__ unsigned short f2bf(float f) {
    unsigned int u = __float_as_uint(f);
    unsigned int r = (u + 0x7fffu + ((u >> 16) & 1u)) >> 16;  // RNE
    return (unsigned short)r;
}

// ---- K1: prep (blocks 0..63) ++ hist (blocks 64..) ----
__global__ void k_prep_hist(unsigned short* __restrict__ h, _Float16* __restrict__ g,
                            const float* __restrict__ W1, unsigned short* __restrict__ wt,
                            int n, const int* __restrict__ dst, int E,
                            int* __restrict__ hist, int nbuck, float* __restrict__ dinv) {
    __shared__ int lh[MAXBK];
    const int t = threadIdx.x;
    if (blockIdx.x < 64) {  // prep: wt = bf16(W1^T); dummy rows h[n]=0, g[n]=0
        int i = blockIdx.x * 256 + t;
        if (i < 16384) {
            int nc = i >> 7, k = i & 127;
            wt[i] = f2bf(W1[k * 128 + nc]);
        }
        if (i < 128) h[(size_t)n * 128 + i] = 0;
        if (i < 16) g[(size_t)n * 16 + i] = (_Float16)0.f;
        if (i < 1) dinv[n] = 1.f;  // pad neighbors: finite scale x zero row
        return;
    }
    const int blk = blockIdx.x - 64;
    for (int i = t; i < nbuck; i += 256) lh[i] = 0;
    __syncthreads();
    const int e0 = blk * EPB;
    const int e1 = min(e0 + EPB, E);
    for (int e = e0 + t; e < e1; e += 256)
        atomicAdd(&lh[dst[e] >> BSH], 1);
    __syncthreads();
    for (int i = t; i < nbuck; i += 256)
        hist[blk * nbuck + i] = lh[i];
}

// ---- K2: one block per bucket (196-way parallel; replaces single-block scan)
// hist[blk][b] -> LOCAL exclusive prefix over blk; bcount[b] = column total.
// (requires neb <= 128)
__global__ __launch_bounds__(128) void k_colsum(int* __restrict__ hist,
                                                int* __restrict__ bcount,
                                                int neb, int nbuck) {
    __shared__ int v[128];
    __shared__ int p[128];
    const int t = threadIdx.x, b = blockIdx.x;
    int x = 0;
    if (t < neb) x = hist[t * nbuck + b];
    v[t] = x;
    p[t] = x;
    __syncthreads();
    for (int o = 1; o < 128; o <<= 1) {
        int y = 0;
        if (t >= o) y = p[t - o];
        __syncthreads();
        p[t] += y;
        __syncthreads();
    }
    if (t < neb) hist[t * nbuck + b] = p[t] - v[t];  // local exclusive prefix
    if (t == 127) bcount[b] = p[127];                // column total
}

// ---- K3: bin (blocks 0..neb-1) ++ gemm1 (blocks neb..) ----
// bin: in-block scan of bcount -> bstart; cursor = bstart + local prefix.
__global__ __launch_bounds__(256) void k_bin_gemm(
        const int* __restrict__ src, const int* __restrict__ dst, int E,
        const int* __restrict__ hist, const int* __restrict__ bcount,
        int* __restrict__ binned, int nbuck, int neb,
        const float* __restrict__ x, const unsigned short* __restrict__ wt,
        unsigned short* __restrict__ h, int n) {
    __shared__ unsigned short xs[64 * 136];  // 17.4 KB; bin aliases front ~2.8KB
    const int t = threadIdx.x;
    if ((int)blockIdx.x < neb) {
        int* cnt = (int*)xs;               // [MAXBK]
        int* ps  = ((int*)xs) + MAXBK;     // [256]
        int* ex  = ((int*)xs) + MAXBK + 256;  // [256]
        const int blk = blockIdx.x;
        int myc = (t < nbuck) ? bcount[t] : 0;
        ps[t] = myc;
        __syncthreads();
        for (int o = 1; o < 256; o <<= 1) {
            int y = 0;
            if (t >= o) y = ps[t - o];
            __syncthreads();
            ps[t] += y;
            __syncthreads();
        }
        ex[t] = ps[t] - myc;  // bstart[t]
        __syncthreads();
        if (t < nbuck) cnt[t] = ex[t] + hist[blk * nbuck + t];
        __syncthreads();
        const int e0 = blk * EPB;
        const int e1 = min(e0 + EPB, E);
        for (int e = e0 + t; e < e1; e += 256) {
            int d = dst[e];
            int b = d >> BSH;
            int pos = atomicAdd(&cnt[b], 1);
            binned[pos] = src[e] | ((d & ((1 << BSH) - 1)) << 17);
        }
        return;
    }
    // ---- gemm1: h' = x @ W1 (bf16 MFMA, UNSCALED), 64 rows/block ----
    const int row0 = ((int)blockIdx.x - neb) * 64;
    for (int i = t; i < 2048; i += 256) {
        int r = i >> 5, c4 = (i & 31) << 2;
        int gr = row0 + r;
        float4 v = make_float4(0.f, 0.f, 0.f, 0.f);
        if (gr < n) v = *(const float4*)(x + (size_t)gr * 128 + c4);
        ushort4 u;
        u.x = f2bf(v.x); u.y = f2bf(v.y); u.z = f2bf(v.z); u.w = f2bf(v.w);
        *(ushort4*)(xs + r * 136 + c4) = u;
    }
    __syncthreads();
    const int w = t >> 6;
    const int lane = t & 63;
    const int m = lane & 15, q = lane >> 4;
    f32x4 acc[8];
#pragma unroll
    for (int ns = 0; ns < 8; ++ns) acc[ns] = (f32x4){0.f, 0.f, 0.f, 0.f};
#pragma unroll
    for (int kt = 0; kt < 4; ++kt) {
        short8 a = *(const short8*)(xs + (w * 16 + m) * 136 + kt * 32 + q * 8);
#pragma unroll
        for (int ns = 0; ns < 8; ++ns) {
            short8 b = *(const short8*)((const short*)wt + (ns * 16 + m) * 128 + kt * 32 + q * 8);
            acc[ns] = __builtin_amdgcn_mfma_f32_16x16x32_bf16(a, b, acc[ns], 0, 0, 0);
        }
    }
    unsigned short* xsw = xs + (w * 16) * 136;
#pragma unroll
    for (int ns = 0; ns < 8; ++ns)
#pragma unroll
        for (int reg = 0; reg < 4; ++reg)
            xsw[(q * 4 + reg) * 136 + ns * 16 + m] = f2bf(acc[ns][reg]);
    __syncthreads();
#pragma unroll
    for (int it = 0; it < 8; ++it) {
        int rl = (lane >> 5) + it * 2;
        int off = (lane & 31) * 4;
        int gr = row0 + w * 16 + rl;
        if (gr < n)
            *(ushort4*)(h + (size_t)gr * 128 + off) = *(const ushort4*)(xsw + rl * 136 + off);
    }
}

// ---- K4: one block per bucket. LDS counting sort -> coalesced col writes ----
__global__ __launch_bounds__(256) void k_ell(
        const int* __restrict__ binned, const int* __restrict__ bcount,
        int* __restrict__ deg, float* __restrict__ dinv, int* __restrict__ col,
        int n, int nbuck) {
    __shared__ int sorted[SORTCAP];   // 40 KB
    __shared__ int ldeg[1 << BSH];
    __shared__ int off[1 << BSH];
    __shared__ int cur[1 << BSH];
    __shared__ int psum[256];
    __shared__ int s_st, s_cv;
    const int t = threadIdx.x, b = blockIdx.x;
    const int node0 = b << BSH;
    // in-block bstart: exclusive scan of bcount up to b
    int myc = (t < nbuck) ? bcount[t] : 0;
    psum[t] = myc;
    __syncthreads();
    for (int o = 1; o < 256; o <<= 1) {
        int y = 0;
        if (t >= o) y = psum[t - o];
        __syncthreads();
        psum[t] += y;
        __syncthreads();
    }
    if (t == b) { s_st = psum[b] - myc; s_cv = myc; }
    for (int i = t; i < (1 << BSH); i += 256) { ldeg[i] = 0; cur[i] = 0; }
    __syncthreads();
    const int st = s_st, cv = s_cv;
    // pass 1: per-node histogram (coalesced binned reads)
    for (int i = t; i < cv; i += 256)
        atomicAdd(&ldeg[binned[st + i] >> 17], 1);
    __syncthreads();

    if (cv <= SORTCAP) {
        // clamped exclusive prefix over 512 nodes (2/thread + H-S scan)
        int c0 = min(ldeg[2 * t], ELLW);
        int c1 = min(ldeg[2 * t + 1], ELLW);
        psum[t] = c0 + c1;
        __syncthreads();
        for (int o = 1; o < 256; o <<= 1) {
            int v = 0;
            if (t >= o) v = psum[t - o];
            __syncthreads();
            psum[t] += v;
            __syncthreads();
        }
        int base = psum[t] - (c0 + c1);
        off[2 * t] = base;
        off[2 * t + 1] = base + c0;
        __syncthreads();
        // pass 2: scatter into sorted LDS (clamped)
        for (int i = t; i < cv; i += 256) {
            int v = binned[st + i];
            int dl = v >> 17;
            int r = atomicAdd(&cur[dl], 1);
            if (r < ELLW) sorted[off[dl] + r] = v & 0x1FFFF;
        }
        __syncthreads();
        // linear col write: int4, fully coalesced; pad with dummy node n
        const int nn = min(1 << BSH, n - node0);
        const int totv = nn * (ELLW / 4);
        int* colb = col + (size_t)node0 * ELLW;
        for (int idx = t; idx < totv; idx += 256) {
            int i = idx / (ELLW / 4);
            int q = (idx - i * (ELLW / 4)) * 4;
            int dc = min(ldeg[i], ELLW);
            int o = off[i];
            i32x4 v;
#pragma unroll
            for (int j = 0; j < 4; ++j)
                v[j] = (q + j < dc) ? sorted[o + q + j] : n;
            *(i32x4*)(colb + (size_t)i * ELLW + q) = v;
        }
    } else {
        // fallback (never expected): old scatter path
        for (int i = t; i < cv; i += 256) {
            int v = binned[st + i];
            int s = v & 0x1FFFF;
            int dl = v >> 17;
            int r = atomicAdd(&cur[dl], 1);
            if (r < ELLW) col[(size_t)(node0 + dl) * ELLW + r] = s;
        }
        __syncthreads();
        for (int i = t; i < (1 << BSH); i += 256) {
            int node = node0 + i;
            if (node < n) {
                int dc = min(ldeg[i], ELLW);
                int kend = (dc + 7) & ~7;
                for (int q = dc; q < kend; ++q) col[(size_t)node * ELLW + q] = n;
            }
        }
    }
    // deg + dinv (coalesced)
    for (int i = t; i < (1 << BSH); i += 256) {
        int node = node0 + i;
        if (node < n) {
            int dgv = ldeg[i];
            deg[node] = dgv;
            dinv[node] = rsqrtf((float)(min(dgv, ELLW) + 1));
        }
    }
}

// ---- fused gather1 + relu + (128->16 matvec) + scale. g stored fp16. ----
__global__ __launch_bounds__(256, 2) void k_gather1f(
        const unsigned short* __restrict__ h, const int* __restrict__ deg,
        const float* __restrict__ dinv, const int* __restrict__ col,
        const float* __restrict__ b1, const float* __restrict__ W2,
        _Float16* __restrict__ g, int n) {
    const int t = threadIdx.x;
    const int lane = t & 15;
    const int d = blockIdx.x * 16 + (t >> 4);
    if (d >= n) return;
    int dg = deg[d];
    if (dg > ELLW) dg = ELLW;
    const float dd = dinv[d];
    const int kend = (dg + 7) & ~7;
    const int* ecol = col + (size_t)d * ELLW;

    float aA[8], aB[8];
    {   // self row: dinv[d] * h[d]
        short8 u = *(const short8*)(h + (size_t)d * 128 + lane * 8);
#pragma unroll
        for (int j = 0; j < 8; ++j) {
            aA[j] = dd * bf2f((unsigned short)u[j]);
            aB[j] = 0.f;
        }
    }
    for (int k = 0; k < kend; k += 8) {  // padded: full batches of 8
        int4 c0 = *(const int4*)(ecol + k);
        int4 c1 = *(const int4*)(ecol + k + 4);
        float e0 = dinv[c0.x], e1 = dinv[c0.y], e2 = dinv[c0.z], e3 = dinv[c0.w];
        float e4 = dinv[c1.x], e5 = dinv[c1.y], e6 = dinv[c1.z], e7 = dinv[c1.w];
        short8 u0 = *(const short8*)(h + (size_t)c0.x * 128 + lane * 8);
        short8 u1 = *(const short8*)(h + (size_t)c0.y * 128 + lane * 8);
        short8 u2 = *(const short8*)(h + (size_t)c0.z * 128 + lane * 8);
        short8 u3 = *(const short8*)(h + (size_t)c0.w * 128 + lane * 8);
        short8 u4 = *(const short8*)(h + (size_t)c1.x * 128 + lane * 8);
        short8 u5 = *(const short8*)(h + (size_t)c1.y * 128 + lane * 8);
        short8 u6 = *(const short8*)(h + (size_t)c1.z * 128 + lane * 8);
        short8 u7 = *(const short8*)(h + (size_t)c1.w * 128 + lane * 8);
#pragma unroll
        for (int j = 0; j < 8; ++j) {
            aA[j] = fmaf(bf2f((unsigned short)u0[j]), e0, aA[j]);
            aB[j] = fmaf(bf2f((unsigned short)u1[j]), e1, aB[j]);
            aA[j] = fmaf(bf2f((unsigned short)u2[j]), e2, aA[j]);
            aB[j] = fmaf(bf2f((unsigned short)u3[j]), e3, aB[j]);
            aA[j] = fmaf(bf2f((unsigned short)u4[j]), e4, aA[j]);
            aB[j] = fmaf(bf2f((unsigned short)u5[j]), e5, aB[j]);
            aA[j] = fmaf(bf2f((unsigned short)u6[j]), e6, aA[j]);
            aB[j] = fmaf(bf2f((unsigned short)u7[j]), e7, aB[j]);
        }
    }
    float y[8];
    const float* b1p = b1 + lane * 8;
#pragma unroll
    for (int j = 0; j < 8; ++j)
        y[j] = fmaxf(fmaf(aA[j] + aB[j], dd, b1p[j]), 0.f);
    const float4* w2v = (const float4*)(W2 + lane * 8 * 16);
    float4 z0 = make_float4(0.f, 0.f, 0.f, 0.f);
    float4 z1 = z0, z2 = z0, z3 = z0;
#pragma unroll
    for (int j = 0; j < 8; ++j) {
        float4 w0 = w2v[j * 4 + 0], w1 = w2v[j * 4 + 1];
        float4 w2 = w2v[j * 4 + 2], w3 = w2v[j * 4 + 3];
        float yj = y[j];
        z0.x = fmaf(yj, w0.x, z0.x); z0.y = fmaf(yj, w0.y, z0.y);
        z0.z = fmaf(yj, w0.z, z0.z); z0.w = fmaf(yj, w0.w, z0.w);
        z1.x = fmaf(yj, w1.x, z1.x); z1.y = fmaf(yj, w1.y, z1.y);
        z1.z = fmaf(yj, w1.z, z1.z); z1.w = fmaf(yj, w1.w, z1.w);
        z2.x = fmaf(yj, w2.x, z2.x); z2.y = fmaf(yj, w2.y, z2.y);
        z2.z = fmaf(yj, w2.z, z2.z); z2.w = fmaf(yj, w2.w, z2.w);
        z3.x = fmaf(yj, w3.x, z3.x); z3.y = fmaf(yj, w3.y, z3.y);
        z3.z = fmaf(yj, w3.z, z3.z); z3.w = fmaf(yj, w3.w, z3.w);
    }
#pragma unroll
    for (int mm = 1; mm < 16; mm <<= 1) {
        z0.x += __shfl_xor(z0.x, mm); z0.y += __shfl_xor(z0.y, mm);
        z0.z += __shfl_xor(z0.z, mm); z0.w += __shfl_xor(z0.w, mm);
        z1.x += __shfl_xor(z1.x, mm); z1.y += __shfl_xor(z1.y, mm);
        z1.z += __shfl_xor(z1.z, mm); z1.w += __shfl_xor(z1.w, mm);
        z2.x += __shfl_xor(z2.x, mm); z2.y += __shfl_xor(z2.y, mm);
        z2.z += __shfl_xor(z2.z, mm); z2.w += __shfl_xor(z2.w, mm);
        z3.x += __shfl_xor(z3.x, mm); z3.y += __shfl_xor(z3.y, mm);
        z3.z += __shfl_xor(z3.z, mm); z3.w += __shfl_xor(z3.w, mm);
    }
    if (lane < 4) {
        float4 z = (lane == 0) ? z0 : (lane == 1) ? z1 : (lane == 2) ? z2 : z3;
        f16x4 zz;
        zz[0] = (_Float16)(z.x * dd); zz[1] = (_Float16)(z.y * dd);
        zz[2] = (_Float16)(z.z * dd); zz[3] = (_Float16)(z.w * dd);
        *(f16x4*)(g + (size_t)d * 16 + lane * 4) = zz;  // 8B store, 32B row
    }
}

// ---- gather2: 2 lanes/node, f16x8 (16B) loads + bias + log_softmax ----
__global__ void k_gather2(const _Float16* __restrict__ g, const int* __restrict__ deg,
                          const int* __restrict__ col, const float* __restrict__ b2,
                          float* __restrict__ out, int n) {
    const int t = threadIdx.x;
    const int d = blockIdx.x * 128 + (t >> 1);
    if (d >= n) return;
    const int l = t & 1;
    int dg = deg[d];
    if (dg > ELLW) dg = ELLW;
    const float dd = rsqrtf((float)(dg + 1));
    const int kend = (dg + 7) & ~7;
    const int* ecol = col + (size_t)d * ELLW;
    const _Float16* gl = g + l * 8;

    float aA[8], aB[8];
    {   // self
        f16x8 s = *(const f16x8*)(gl + (size_t)d * 16);
#pragma unroll
        for (int j = 0; j < 8; ++j) { aA[j] = (float)s[j]; aB[j] = 0.f; }
    }
    for (int k = 0; k < kend; k += 8) {
        int4 c0 = *(const int4*)(ecol + k);
        int4 c1 = *(const int4*)(ecol + k + 4);
        f16x8 u0 = *(const f16x8*)(gl + (size_t)c0.x * 16);
        f16x8 u1 = *(const f16x8*)(gl + (size_t)c0.y * 16);
        f16x8 u2 = *(const f16x8*)(gl + (size_t)c0.z * 16);
        f16x8 u3 = *(const f16x8*)(gl + (size_t)c0.w * 16);
        f16x8 u4 = *(const f16x8*)(gl + (size_t)c1.x * 16);
        f16x8 u5 = *(const f16x8*)(gl + (size_t)c1.y * 16);
        f16x8 u6 = *(const f16x8*)(gl + (size_t)c1.z * 16);
        f16x8 u7 = *(const f16x8*)(gl + (size_t)c1.w * 16);
#pragma unroll
        for (int j = 0; j < 8; ++j) {
            aA[j] += (float)u0[j] + (float)u2[j] + (float)u4[j] + (float)u6[j];
            aB[j] += (float)u1[j] + (float)u3[j] + (float)u5[j] + (float)u7[j];
        }
    }
    float acc[8];
    const float* b2p = b2 + l * 8;
#pragma unroll
    for (int j = 0; j < 8; ++j) acc[j] = fmaf(aA[j] + aB[j], dd, b2p[j]);
    f32x4 o0 = {acc[0], acc[1], acc[2], acc[3]};
    f32x4 o1 = {acc[4], acc[5], acc[6], acc[7]};
    *(f32x4*)(out + (size_t)d * 16 + l * 8) = o0;
    *(f32x4*)(out + (size_t)d * 16 + l * 8 + 4) = o1;
    float m = acc[0];
#pragma unroll
    for (int j = 1; j < 8; ++j) m = fmaxf(m, acc[j]);
    m = fmaxf(m, __shfl_xor(m, 1));  // partner lane shares node (d = t>>1)
    float e = 0.f;
#pragma unroll
    for (int j = 0; j < 8; ++j) e += expf(acc[j] - m);
    e += __shfl_xor(e, 1);
    float ls = m + logf(e);
    f32x4 p0, p1;
#pragma unroll
    for (int j = 0; j < 4; ++j) { p0[j] = acc[j] - ls; p1[j] = acc[j + 4] - ls; }
    float* ob = out + (size_t)n * 16 + (size_t)d * 16 + l * 8;
    *(f32x4*)(ob) = p0;
    *(f32x4*)(ob + 4) = p1;
}

static inline size_t align256(size_t v) { return (v + 255) & ~(size_t)255; }

extern "C" void kernel_launch(void* const* d_in, const int* in_sizes, int n_in,
                              void* d_out, int out_size, void* d_ws, size_t ws_size,
                              hipStream_t stream) {
    const float* x  = (const float*)d_in[0];
    const int*   ei = (const int*)d_in[1];
    const float* W1 = (const float*)d_in[2];
    const float* b1 = (const float*)d_in[3];
    const float* W2 = (const float*)d_in[4];
    const float* b2 = (const float*)d_in[5];
    float* out = (float*)d_out;

    const int n = in_sizes[0] / 128;  // 100000
    const int E = in_sizes[1] / 2;    // 1600000
    const int* src = ei;
    const int* dst = ei + E;
    const int NEB = (E + EPB - 1) / EPB;            // 98 (<= 128 for colsum)
    const int NBUCK = (n + (1 << BSH) - 1) >> BSH;  // 196 (<= MAXBK)

    // workspace layout, 256B-aligned (~65.5 MB)
    char* base = (char*)d_ws;
    size_t off = 0;
    int* deg = (int*)(base + off); off = align256(off + (size_t)n * 4);
    float* dinv = (float*)(base + off); off = align256(off + ((size_t)n + 1) * 4);
    int* col = (int*)(base + off); off = align256(off + (size_t)n * ELLW * 4);
    unsigned short* wt = (unsigned short*)(base + off); off = align256(off + 128 * 128 * 2);
    unsigned short* h = (unsigned short*)(base + off); off = align256(off + ((size_t)n + 1) * 128 * 2);
    _Float16* g = (_Float16*)(base + off); off = align256(off + ((size_t)n + 1) * 16 * 2);
    int* hist = (int*)(base + off); off = align256(off + (size_t)MAXEB * MAXBK * 4);
    int* bcount = (int*)(base + off); off = align256(off + (size_t)MAXBK * 4);
    int* binned = (int*)(base + off); off = align256(off + (size_t)E * 4);

    // adjacency build (no device atomics); prep fused into hist launch
    k_prep_hist<<<64 + NEB, 256, 0, stream>>>(h, g, W1, wt, n, dst, E, hist, NBUCK, dinv);
    k_colsum<<<NBUCK, 128, 0, stream>>>(hist, bcount, NEB, NBUCK);
    // bin ++ gemm1 (gemm needs only wt; h unscaled -> no deg dependency)
    k_bin_gemm<<<NEB + (n + 63) / 64, 256, 0, stream>>>(
        src, dst, E, hist, bcount, binned, NBUCK, NEB, x, wt, h, n);
    k_ell<<<NBUCK, 256, 0, stream>>>(binned, bcount, deg, dinv, col, n, NBUCK);

    // layer 1 fused gather (per-neighbor dinv fma) + relu + matvec
    k_gather1f<<<(n + 15) / 16, 256, 0, stream>>>(h, deg, dinv, col, b1, W2, g, n);

    // layer 2 aggregation (+ fused bias/softmax)
    k_gather2<<<(n + 127) / 128, 256, 0, stream>>>(g, deg, col, b2, out, n);
}

// Round 8
// 337.804 us; speedup vs baseline: 1.0245x; 1.0245x over previous
//
#include <hip/hip_runtime.h>
#include <math.h>

// ---------------------------------------------------------------------------
// GCN 2-layer forward. ELL adjacency via FIXED-REGION binning (no hist/scan):
//   K1 k_prep     : wt = bf16(W1^T), dummy rows h[n]=0 g[n]=0, zero gcursor
//   K2 k_bin_gemm : [bin blocks: LDS chunk-hist -> 1 atomicAdd(gcursor[b],cnt)
//                    per (block,bucket) -> scatter into bucket's fixed BCAP
//                    region] ++ [gemm blocks: h' = x @ W1, bf16 MFMA, unscaled]
//   K3 k_ell      : one block per bucket: LDS counting sort -> coalesced int4
//                    col writes; writes deg[] and dinv[]
//   K4 k_gather1f : gather h*dinv[src] + relu + (128->16 matvec) -> g [fp16]
//   K5 k_gather2  : gather g (fp16, 2 lanes/node 16B) + bias + log_softmax
// r0-r7 findings: gather1f pinned at ~125-131us / ~192-198MB FETCH / 1.6 TB/s
// across 7 schedules -> L2<->LLC fabric floor for random 256B rows; closed.
// Within-kernel tweaks (SW pipeline r1, nt hints r3, sort r6, scan/gather2 r7)
// are null; only LAUNCH REMOVAL moved the total (r4, r5). This rev deletes
// the hist pass + colsum kernel entirely via fixed-region agg-atomic binning.
// ---------------------------------------------------------------------------

#define ELLW 72       // multiple of 8 (deg~Poisson(16); no clamp in practice)
#define EPB 16384     // edges per bin block
#define BSH 9         // bucket = 512 nodes
#define MAXBK 200     // >= ceil(n/512) = 196
#define BCAP 10240    // per-bucket binned region (mean 8192, sigma~90 -> 22s)

typedef __attribute__((ext_vector_type(8))) short short8;
typedef __attribute__((ext_vector_type(4))) float f32x4;
typedef __attribute__((ext_vector_type(4))) int i32x4;
typedef __attribute__((ext_vector_type(4))) _Float16 f16x4;
typedef __attribute__((ext_vector_type(8))) _Float16 f16x8;

__device__ __forceinline__ float bf2f(unsigned short u) {
    return __uint_as_float(((unsigned int)u) << 16);
}
__device__ __forceinline__ unsigned short f2bf(float f) {
    unsigned int u = __float_as_uint(f);
    unsigned int r = (u + 0x7fffu + ((u >> 16) & 1u)) >> 16;  // RNE
    return (unsigned short)r;
}

// ---- K1: prep. 65 blocks: wt (0..63), gcursor zero + dummies (64) ----
__global__ void k_prep(unsigned short* __restrict__ h, _Float16* __restrict__ g,
                       const float* __restrict__ W1, unsigned short* __restrict__ wt,
                       int n, int* __restrict__ gcursor, float* __restrict__ dinv) {
    const int t = threadIdx.x;
    int i = blockIdx.x * 256 + t;
    if (i < 16384) {  // wt[nc][k] = bf16(W1[k][nc])
        int nc = i >> 7, k = i & 127;
        wt[i] = f2bf(W1[k * 128 + nc]);
    }
    if (blockIdx.x == 64) {
        if (t < MAXBK) gcursor[t] = 0;
    }
    if (i < 128) h[(size_t)n * 128 + i] = 0;
    if (i < 16) g[(size_t)n * 16 + i] = (_Float16)0.f;
    if (i < 1) dinv[n] = 1.f;  // pad neighbors: finite scale x zero row
}

// ---- K2: bin (blocks 0..neb-1) ++ gemm1 (blocks neb..) ----
// bin: pass1 LDS hist of chunk; one global atomicAdd per (block,bucket) for
// the base; pass2 scatter (src | dstLow<<17) into bucket's fixed region.
__global__ __launch_bounds__(256) void k_bin_gemm(
        const int* __restrict__ src, const int* __restrict__ dst, int E,
        int* __restrict__ gcursor, int* __restrict__ binned, int nbuck, int neb,
        const float* __restrict__ x, const unsigned short* __restrict__ wt,
        unsigned short* __restrict__ h, int n) {
    __shared__ unsigned short xs[64 * 136];  // 17.4 KB; bin aliases front 800 B
    const int t = threadIdx.x;
    if ((int)blockIdx.x < neb) {
        int* cnt = (int*)xs;  // [MAXBK]: counts, then absolute-relative cursors
        const int blk = blockIdx.x;
        for (int i = t; i < nbuck; i += 256) cnt[i] = 0;
        __syncthreads();
        const int e0 = blk * EPB;
        const int e1 = min(e0 + EPB, E);
        for (int e = e0 + t; e < e1; e += 256)
            atomicAdd(&cnt[dst[e] >> BSH], 1);
        __syncthreads();
        if (t < nbuck) {
            int c = cnt[t];
            cnt[t] = c ? atomicAdd(&gcursor[t], c) : 0;  // region-relative base
        }
        __syncthreads();
        for (int e = e0 + t; e < e1; e += 256) {
            int d = dst[e];
            int b = d >> BSH;
            int r = atomicAdd(&cnt[b], 1);
            if (r < BCAP)
                binned[(size_t)b * BCAP + r] = src[e] | ((d & ((1 << BSH) - 1)) << 17);
        }
        return;
    }
    // ---- gemm1: h' = x @ W1 (bf16 MFMA, UNSCALED), 64 rows/block ----
    const int row0 = ((int)blockIdx.x - neb) * 64;
    for (int i = t; i < 2048; i += 256) {
        int r = i >> 5, c4 = (i & 31) << 2;
        int gr = row0 + r;
        float4 v = make_float4(0.f, 0.f, 0.f, 0.f);
        if (gr < n) v = *(const float4*)(x + (size_t)gr * 128 + c4);
        ushort4 u;
        u.x = f2bf(v.x); u.y = f2bf(v.y); u.z = f2bf(v.z); u.w = f2bf(v.w);
        *(ushort4*)(xs + r * 136 + c4) = u;
    }
    __syncthreads();
    const int w = t >> 6;
    const int lane = t & 63;
    const int m = lane & 15, q = lane >> 4;
    f32x4 acc[8];
#pragma unroll
    for (int ns = 0; ns < 8; ++ns) acc[ns] = (f32x4){0.f, 0.f, 0.f, 0.f};
#pragma unroll
    for (int kt = 0; kt < 4; ++kt) {
        short8 a = *(const short8*)(xs + (w * 16 + m) * 136 + kt * 32 + q * 8);
#pragma unroll
        for (int ns = 0; ns < 8; ++ns) {
            short8 b = *(const short8*)((const short*)wt + (ns * 16 + m) * 128 + kt * 32 + q * 8);
            acc[ns] = __builtin_amdgcn_mfma_f32_16x16x32_bf16(a, b, acc[ns], 0, 0, 0);
        }
    }
    unsigned short* xsw = xs + (w * 16) * 136;
#pragma unroll
    for (int ns = 0; ns < 8; ++ns)
#pragma unroll
        for (int reg = 0; reg < 4; ++reg)
            xsw[(q * 4 + reg) * 136 + ns * 16 + m] = f2bf(acc[ns][reg]);
    __syncthreads();
#pragma unroll
    for (int it = 0; it < 8; ++it) {
        int rl = (lane >> 5) + it * 2;
        int off = (lane & 31) * 4;
        int gr = row0 + w * 16 + rl;
        if (gr < n)
            *(ushort4*)(h + (size_t)gr * 128 + off) = *(const ushort4*)(xsw + rl * 136 + off);
    }
}

// ---- K3: one block per bucket. LDS counting sort -> coalesced col writes ----
__global__ __launch_bounds__(256) void k_ell(
        const int* __restrict__ binned, const int* __restrict__ gcursor,
        int* __restrict__ deg, float* __restrict__ dinv, int* __restrict__ col,
        int n) {
    __shared__ int sorted[BCAP];      // 40 KB
    __shared__ int ldeg[1 << BSH];
    __shared__ int off[1 << BSH];
    __shared__ int cur[1 << BSH];
    __shared__ int psum[256];
    const int t = threadIdx.x, b = blockIdx.x;
    const int node0 = b << BSH;
    const size_t st = (size_t)b * BCAP;
    int cv = gcursor[b];
    if (cv > BCAP) cv = BCAP;
    for (int i = t; i < (1 << BSH); i += 256) { ldeg[i] = 0; cur[i] = 0; }
    __syncthreads();
    // pass 1: per-node histogram (coalesced binned reads)
    for (int i = t; i < cv; i += 256)
        atomicAdd(&ldeg[binned[st + i] >> 17], 1);
    __syncthreads();
    // clamped exclusive prefix over 512 nodes (2/thread + H-S scan)
    int c0 = min(ldeg[2 * t], ELLW);
    int c1 = min(ldeg[2 * t + 1], ELLW);
    psum[t] = c0 + c1;
    __syncthreads();
    for (int o = 1; o < 256; o <<= 1) {
        int v = 0;
        if (t >= o) v = psum[t - o];
        __syncthreads();
        psum[t] += v;
        __syncthreads();
    }
    int base = psum[t] - (c0 + c1);
    off[2 * t] = base;
    off[2 * t + 1] = base + c0;
    __syncthreads();
    // pass 2: scatter into sorted LDS (clamped; sum of clamps <= cv <= BCAP)
    for (int i = t; i < cv; i += 256) {
        int v = binned[st + i];
        int dl = v >> 17;
        int r = atomicAdd(&cur[dl], 1);
        if (r < ELLW) sorted[off[dl] + r] = v & 0x1FFFF;
    }
    __syncthreads();
    // linear col write: int4, fully coalesced; pad with dummy node n
    const int nn = min(1 << BSH, n - node0);
    const int totv = nn * (ELLW / 4);
    int* colb = col + (size_t)node0 * ELLW;
    for (int idx = t; idx < totv; idx += 256) {
        int i = idx / (ELLW / 4);
        int q = (idx - i * (ELLW / 4)) * 4;
        int dc = min(ldeg[i], ELLW);
        int o = off[i];
        i32x4 v;
#pragma unroll
        for (int j = 0; j < 4; ++j)
            v[j] = (q + j < dc) ? sorted[o + q + j] : n;
        *(i32x4*)(colb + (size_t)i * ELLW + q) = v;
    }
    // deg + dinv (coalesced)
    for (int i = t; i < (1 << BSH); i += 256) {
        int node = node0 + i;
        if (node < n) {
            int dgv = ldeg[i];
            deg[node] = dgv;
            dinv[node] = rsqrtf((float)(min(dgv, ELLW) + 1));
        }
    }
}

// ---- K4: fused gather1 + relu + (128->16 matvec) + scale. g stored fp16 ----
__global__ __launch_bounds__(256, 2) void k_gather1f(
        const unsigned short* __restrict__ h, const int* __restrict__ deg,
        const float* __restrict__ dinv, const int* __restrict__ col,
        const float* __restrict__ b1, const float* __restrict__ W2,
        _Float16* __restrict__ g, int n) {
    const int t = threadIdx.x;
    const int lane = t & 15;
    const int d = blockIdx.x * 16 + (t >> 4);
    if (d >= n) return;
    int dg = deg[d];
    if (dg > ELLW) dg = ELLW;
    const float dd = dinv[d];
    const int kend = (dg + 7) & ~7;
    const int* ecol = col + (size_t)d * ELLW;

    float aA[8], aB[8];
    {   // self row: dinv[d] * h[d]
        short8 u = *(const short8*)(h + (size_t)d * 128 + lane * 8);
#pragma unroll
        for (int j = 0; j < 8; ++j) {
            aA[j] = dd * bf2f((unsigned short)u[j]);
            aB[j] = 0.f;
        }
    }
    for (int k = 0; k < kend; k += 8) {  // padded: full batches of 8
        int4 c0 = *(const int4*)(ecol + k);
        int4 c1 = *(const int4*)(ecol + k + 4);
        float e0 = dinv[c0.x], e1 = dinv[c0.y], e2 = dinv[c0.z], e3 = dinv[c0.w];
        float e4 = dinv[c1.x], e5 = dinv[c1.y], e6 = dinv[c1.z], e7 = dinv[c1.w];
        short8 u0 = *(const short8*)(h + (size_t)c0.x * 128 + lane * 8);
        short8 u1 = *(const short8*)(h + (size_t)c0.y * 128 + lane * 8);
        short8 u2 = *(const short8*)(h + (size_t)c0.z * 128 + lane * 8);
        short8 u3 = *(const short8*)(h + (size_t)c0.w * 128 + lane * 8);
        short8 u4 = *(const short8*)(h + (size_t)c1.x * 128 + lane * 8);
        short8 u5 = *(const short8*)(h + (size_t)c1.y * 128 + lane * 8);
        short8 u6 = *(const short8*)(h + (size_t)c1.z * 128 + lane * 8);
        short8 u7 = *(const short8*)(h + (size_t)c1.w * 128 + lane * 8);
#pragma unroll
        for (int j = 0; j < 8; ++j) {
            aA[j] = fmaf(bf2f((unsigned short)u0[j]), e0, aA[j]);
            aB[j] = fmaf(bf2f((unsigned short)u1[j]), e1, aB[j]);
            aA[j] = fmaf(bf2f((unsigned short)u2[j]), e2, aA[j]);
            aB[j] = fmaf(bf2f((unsigned short)u3[j]), e3, aB[j]);
            aA[j] = fmaf(bf2f((unsigned short)u4[j]), e4, aA[j]);
            aB[j] = fmaf(bf2f((unsigned short)u5[j]), e5, aB[j]);
            aA[j] = fmaf(bf2f((unsigned short)u6[j]), e6, aA[j]);
            aB[j] = fmaf(bf2f((unsigned short)u7[j]), e7, aB[j]);
        }
    }
    float y[8];
    const float* b1p = b1 + lane * 8;
#pragma unroll
    for (int j = 0; j < 8; ++j)
        y[j] = fmaxf(fmaf(aA[j] + aB[j], dd, b1p[j]), 0.f);
    const float4* w2v = (const float4*)(W2 + lane * 8 * 16);
    float4 z0 = make_float4(0.f, 0.f, 0.f, 0.f);
    float4 z1 = z0, z2 = z0, z3 = z0;
#pragma unroll
    for (int j = 0; j < 8; ++j) {
        float4 w0 = w2v[j * 4 + 0], w1 = w2v[j * 4 + 1];
        float4 w2 = w2v[j * 4 + 2], w3 = w2v[j * 4 + 3];
        float yj = y[j];
        z0.x = fmaf(yj, w0.x, z0.x); z0.y = fmaf(yj, w0.y, z0.y);
        z0.z = fmaf(yj, w0.z, z0.z); z0.w = fmaf(yj, w0.w, z0.w);
        z1.x = fmaf(yj, w1.x, z1.x); z1.y = fmaf(yj, w1.y, z1.y);
        z1.z = fmaf(yj, w1.z, z1.z); z1.w = fmaf(yj, w1.w, z1.w);
        z2.x = fmaf(yj, w2.x, z2.x); z2.y = fmaf(yj, w2.y, z2.y);
        z2.z = fmaf(yj, w2.z, z2.z); z2.w = fmaf(yj, w2.w, z2.w);
        z3.x = fmaf(yj, w3.x, z3.x); z3.y = fmaf(yj, w3.y, z3.y);
        z3.z = fmaf(yj, w3.z, z3.z); z3.w = fmaf(yj, w3.w, z3.w);
    }
#pragma unroll
    for (int mm = 1; mm < 16; mm <<= 1) {
        z0.x += __shfl_xor(z0.x, mm); z0.y += __shfl_xor(z0.y, mm);
        z0.z += __shfl_xor(z0.z, mm); z0.w += __shfl_xor(z0.w, mm);
        z1.x += __shfl_xor(z1.x, mm); z1.y += __shfl_xor(z1.y, mm);
        z1.z += __shfl_xor(z1.z, mm); z1.w += __shfl_xor(z1.w, mm);
        z2.x += __shfl_xor(z2.x, mm); z2.y += __shfl_xor(z2.y, mm);
        z2.z += __shfl_xor(z2.z, mm); z2.w += __shfl_xor(z2.w, mm);
        z3.x += __shfl_xor(z3.x, mm); z3.y += __shfl_xor(z3.y, mm);
        z3.z += __shfl_xor(z3.z, mm); z3.w += __shfl_xor(z3.w, mm);
    }
    if (lane < 4) {
        float4 z = (lane == 0) ? z0 : (lane == 1) ? z1 : (lane == 2) ? z2 : z3;
        f16x4 zz;
        zz[0] = (_Float16)(z.x * dd); zz[1] = (_Float16)(z.y * dd);
        zz[2] = (_Float16)(z.z * dd); zz[3] = (_Float16)(z.w * dd);
        *(f16x4*)(g + (size_t)d * 16 + lane * 4) = zz;  // 8B store, 32B row
    }
}

// ---- K5: gather2, 2 lanes/node f16x8 (16B) loads + bias + log_softmax ----
__global__ void k_gather2(const _Float16* __restrict__ g, const int* __restrict__ deg,
                          const int* __restrict__ col, const float* __restrict__ b2,
                          float* __restrict__ out, int n) {
    const int t = threadIdx.x;
    const int d = blockIdx.x * 128 + (t >> 1);
    if (d >= n) return;
    const int l = t & 1;
    int dg = deg[d];
    if (dg > ELLW) dg = ELLW;
    const float dd = rsqrtf((float)(dg + 1));
    const int kend = (dg + 7) & ~7;
    const int* ecol = col + (size_t)d * ELLW;
    const _Float16* gl = g + l * 8;

    float aA[8], aB[8];
    {   // self
        f16x8 s = *(const f16x8*)(gl + (size_t)d * 16);
#pragma unroll
        for (int j = 0; j < 8; ++j) { aA[j] = (float)s[j]; aB[j] = 0.f; }
    }
    for (int k = 0; k < kend; k += 8) {
        int4 c0 = *(const int4*)(ecol + k);
        int4 c1 = *(const int4*)(ecol + k + 4);
        f16x8 u0 = *(const f16x8*)(gl + (size_t)c0.x * 16);
        f16x8 u1 = *(const f16x8*)(gl + (size_t)c0.y * 16);
        f16x8 u2 = *(const f16x8*)(gl + (size_t)c0.z * 16);
        f16x8 u3 = *(const f16x8*)(gl + (size_t)c0.w * 16);
        f16x8 u4 = *(const f16x8*)(gl + (size_t)c1.x * 16);
        f16x8 u5 = *(const f16x8*)(gl + (size_t)c1.y * 16);
        f16x8 u6 = *(const f16x8*)(gl + (size_t)c1.z * 16);
        f16x8 u7 = *(const f16x8*)(gl + (size_t)c1.w * 16);
#pragma unroll
        for (int j = 0; j < 8; ++j) {
            aA[j] += (float)u0[j] + (float)u2[j] + (float)u4[j] + (float)u6[j];
            aB[j] += (float)u1[j] + (float)u3[j] + (float)u5[j] + (float)u7[j];
        }
    }
    float acc[8];
    const float* b2p = b2 + l * 8;
#pragma unroll
    for (int j = 0; j < 8; ++j) acc[j] = fmaf(aA[j] + aB[j], dd, b2p[j]);
    f32x4 o0 = {acc[0], acc[1], acc[2], acc[3]};
    f32x4 o1 = {acc[4], acc[5], acc[6], acc[7]};
    *(f32x4*)(out + (size_t)d * 16 + l * 8) = o0;
    *(f32x4*)(out + (size_t)d * 16 + l * 8 + 4) = o1;
    float m = acc[0];
#pragma unroll
    for (int j = 1; j < 8; ++j) m = fmaxf(m, acc[j]);
    m = fmaxf(m, __shfl_xor(m, 1));  // partner lane shares node (d = t>>1)
    float e = 0.f;
#pragma unroll
    for (int j = 0; j < 8; ++j) e += expf(acc[j] - m);
    e += __shfl_xor(e, 1);
    float ls = m + logf(e);
    f32x4 p0, p1;
#pragma unroll
    for (int j = 0; j < 4; ++j) { p0[j] = acc[j] - ls; p1[j] = acc[j + 4] - ls; }
    float* ob = out + (size_t)n * 16 + (size_t)d * 16 + l * 8;
    *(f32x4*)(ob) = p0;
    *(f32x4*)(ob + 4) = p1;
}

static inline size_t align256(size_t v) { return (v + 255) & ~(size_t)255; }

extern "C" void kernel_launch(void* const* d_in, const int* in_sizes, int n_in,
                              void* d_out, int out_size, void* d_ws, size_t ws_size,
                              hipStream_t stream) {
    const float* x  = (const float*)d_in[0];
    const int*   ei = (const int*)d_in[1];
    const float* W1 = (const float*)d_in[2];
    const float* b1 = (const float*)d_in[3];
    const float* W2 = (const float*)d_in[4];
    const float* b2 = (const float*)d_in[5];
    float* out = (float*)d_out;

    const int n = in_sizes[0] / 128;  // 100000
    const int E = in_sizes[1] / 2;    // 1600000
    const int* src = ei;
    const int* dst = ei + E;
    const int NEB = (E + EPB - 1) / EPB;            // 98
    const int NBUCK = (n + (1 << BSH) - 1) >> BSH;  // 196 (<= MAXBK)

    // workspace layout, 256B-aligned (~66.1 MB)
    char* base = (char*)d_ws;
    size_t off = 0;
    int* deg = (int*)(base + off); off = align256(off + (size_t)n * 4);
    float* dinv = (float*)(base + off); off = align256(off + ((size_t)n + 1) * 4);
    int* col = (int*)(base + off); off = align256(off + (size_t)n * ELLW * 4);
    unsigned short* wt = (unsigned short*)(base + off); off = align256(off + 128 * 128 * 2);
    unsigned short* h = (unsigned short*)(base + off); off = align256(off + ((size_t)n + 1) * 128 * 2);
    _Float16* g = (_Float16*)(base + off); off = align256(off + ((size_t)n + 1) * 16 * 2);
    int* gcursor = (int*)(base + off); off = align256(off + (size_t)MAXBK * 4);
    int* binned = (int*)(base + off); off = align256(off + (size_t)NBUCK * BCAP * 4);

    // K1: prep (wt, dummies, gcursor=0)
    k_prep<<<65, 256, 0, stream>>>(h, g, W1, wt, n, gcursor, dinv);
    // K2: bin (fixed-region agg-atomic) ++ gemm1
    k_bin_gemm<<<NEB + (n + 63) / 64, 256, 0, stream>>>(
        src, dst, E, gcursor, binned, NBUCK, NEB, x, wt, h, n);
    // K3: ell (counting sort per bucket)
    k_ell<<<NBUCK, 256, 0, stream>>>(binned, gcursor, deg, dinv, col, n);
    // K4: layer-1 fused gather + relu + matvec
    k_gather1f<<<(n + 15) / 16, 256, 0, stream>>>(h, deg, dinv, col, b1, W2, g, n);
    // K5: layer-2 aggregation + bias + log_softmax
    k_gather2<<<(n + 127) / 128, 256, 0, stream>>>(g, deg, col, b2, out, n);
}

// Round 9
// 331.936 us; speedup vs baseline: 1.0426x; 1.0177x over previous
//
#include <hip/hip_runtime.h>
#include <math.h>

// ---------------------------------------------------------------------------
// GCN 2-layer forward. ELL adjacency via FIXED-REGION binning (no hist/scan):
//   M0 memset     : gcursor[MAXBK] = 0
//   K1 k_bin_gemm : [bin blocks: LDS chunk-hist -> 1 atomicAdd(gcursor[b],cnt)
//                    per (block,bucket) -> scatter into bucket's fixed BCAP
//                    region] ++ [gemm blocks: per-block LDS wt=bf16(W1^T),
//                    h' = x @ W1, bf16 MFMA, unscaled]
//   K2 k_ell      : one block per bucket: LDS counting sort -> coalesced int4
//                    col writes; writes deg[]/dinv[]; block 0 writes dummies
//   K3 k_gather1f : gather h*dinv[src] + relu + (128->16 matvec) -> g [fp16]
//   K4 k_gather2  : gather g (fp16, 2 lanes/node 16B) + bias + log_softmax
// r0-r8 findings: gather1f pinned at ~125-131us / ~192-198MB FETCH / 1.6 TB/s
// across 8 schedules -> L2<->LLC fabric floor for random 256B rows; CLOSED.
// Within-kernel tweaks are null (r1/r3/r6/r7); only launch/pass removal moves
// the total (r4 -14, r5 -10, r8 -6). This rev deletes k_prep: gcursor via
// memset, wt built per-gemm-block in LDS, dummy rows written by ell block 0.
// ---------------------------------------------------------------------------

#define ELLW 72       // multiple of 8 (deg~Poisson(16); no clamp in practice)
#define EPB 16384     // edges per bin block
#define BSH 9         // bucket = 512 nodes
#define MAXBK 200     // >= ceil(n/512) = 196
#define BCAP 10240    // per-bucket binned region (mean 8192, sigma~90 -> 22s)

typedef __attribute__((ext_vector_type(8))) short short8;
typedef __attribute__((ext_vector_type(4))) float f32x4;
typedef __attribute__((ext_vector_type(4))) int i32x4;
typedef __attribute__((ext_vector_type(4))) _Float16 f16x4;
typedef __attribute__((ext_vector_type(8))) _Float16 f16x8;

__device__ __forceinline__ float bf2f(unsigned short u) {
    return __uint_as_float(((unsigned int)u) << 16);
}
__device__ __forceinline__ unsigned short f2bf(float f) {
    unsigned int u = __float_as_uint(f);
    unsigned int r = (u + 0x7fffu + ((u >> 16) & 1u)) >> 16;  // RNE
    return (unsigned short)r;
}

// ---- K1: bin (blocks 0..neb-1) ++ gemm1 (blocks neb..) ----
// bin: pass1 LDS hist of chunk; one global atomicAdd per (block,bucket) for
// the base; pass2 scatter (src | dstLow<<17) into bucket's fixed region.
// gemm: stage x-tile AND wt=bf16(W1^T) into LDS, then MFMA. No prep kernel.
__global__ __launch_bounds__(256) void k_bin_gemm(
        const int* __restrict__ src, const int* __restrict__ dst, int E,
        int* __restrict__ gcursor, int* __restrict__ binned, int nbuck, int neb,
        const float* __restrict__ x, const float* __restrict__ W1,
        unsigned short* __restrict__ h, int n) {
    __shared__ unsigned short xs[64 * 136];    // 17.4 KB (bin aliases as cnt)
    __shared__ unsigned short wtl[128 * 136];  // 34.8 KB: wtl[nc][k], padded
    const int t = threadIdx.x;
    if ((int)blockIdx.x < neb) {
        int* cnt = (int*)xs;  // [MAXBK]
        const int blk = blockIdx.x;
        for (int i = t; i < nbuck; i += 256) cnt[i] = 0;
        __syncthreads();
        const int e0 = blk * EPB;
        const int e1 = min(e0 + EPB, E);
        for (int e = e0 + t; e < e1; e += 256)
            atomicAdd(&cnt[dst[e] >> BSH], 1);
        __syncthreads();
        if (t < nbuck) {
            int c = cnt[t];
            cnt[t] = c ? atomicAdd(&gcursor[t], c) : 0;  // region-relative base
        }
        __syncthreads();
        for (int e = e0 + t; e < e1; e += 256) {
            int d = dst[e];
            int b = d >> BSH;
            int r = atomicAdd(&cnt[b], 1);
            if (r < BCAP)
                binned[(size_t)b * BCAP + r] = src[e] | ((d & ((1 << BSH) - 1)) << 17);
        }
        return;
    }
    // ---- gemm1: h' = x @ W1 (bf16 MFMA, UNSCALED), 64 rows/block ----
    const int row0 = ((int)blockIdx.x - neb) * 64;
    for (int i = t; i < 2048; i += 256) {
        int r = i >> 5, c4 = (i & 31) << 2;
        int gr = row0 + r;
        float4 v = make_float4(0.f, 0.f, 0.f, 0.f);
        if (gr < n) v = *(const float4*)(x + (size_t)gr * 128 + c4);
        ushort4 u;
        u.x = f2bf(v.x); u.y = f2bf(v.y); u.z = f2bf(v.z); u.w = f2bf(v.w);
        *(ushort4*)(xs + r * 136 + c4) = u;
    }
    for (int i = t; i < 16384; i += 256) {  // wtl[nc][k] = bf16(W1[k][nc])
        int k = i >> 7, nc = i & 127;
        wtl[nc * 136 + k] = f2bf(W1[i]);
    }
    __syncthreads();
    const int w = t >> 6;
    const int lane = t & 63;
    const int m = lane & 15, q = lane >> 4;
    f32x4 acc[8];
#pragma unroll
    for (int ns = 0; ns < 8; ++ns) acc[ns] = (f32x4){0.f, 0.f, 0.f, 0.f};
#pragma unroll
    for (int kt = 0; kt < 4; ++kt) {
        short8 a = *(const short8*)(xs + (w * 16 + m) * 136 + kt * 32 + q * 8);
#pragma unroll
        for (int ns = 0; ns < 8; ++ns) {
            short8 b = *(const short8*)(wtl + (ns * 16 + m) * 136 + kt * 32 + q * 8);
            acc[ns] = __builtin_amdgcn_mfma_f32_16x16x32_bf16(a, b, acc[ns], 0, 0, 0);
        }
    }
    __syncthreads();  // xs re-use below
    unsigned short* xsw = xs + (w * 16) * 136;
#pragma unroll
    for (int ns = 0; ns < 8; ++ns)
#pragma unroll
        for (int reg = 0; reg < 4; ++reg)
            xsw[(q * 4 + reg) * 136 + ns * 16 + m] = f2bf(acc[ns][reg]);
    __syncthreads();
#pragma unroll
    for (int it = 0; it < 8; ++it) {
        int rl = (lane >> 5) + it * 2;
        int off = (lane & 31) * 4;
        int gr = row0 + w * 16 + rl;
        if (gr < n)
            *(ushort4*)(h + (size_t)gr * 128 + off) = *(const ushort4*)(xsw + rl * 136 + off);
    }
}

// ---- K2: one block per bucket. LDS counting sort -> coalesced col writes.
// Block 0 additionally writes dummy rows h[n]=0, g[n]=0, dinv[n]=1.
__global__ __launch_bounds__(256) void k_ell(
        const int* __restrict__ binned, const int* __restrict__ gcursor,
        int* __restrict__ deg, float* __restrict__ dinv, int* __restrict__ col,
        unsigned short* __restrict__ h, _Float16* __restrict__ g, int n) {
    __shared__ int sorted[BCAP];      // 40 KB
    __shared__ int ldeg[1 << BSH];
    __shared__ int off[1 << BSH];
    __shared__ int cur[1 << BSH];
    __shared__ int psum[256];
    const int t = threadIdx.x, b = blockIdx.x;
    const int node0 = b << BSH;
    const size_t st = (size_t)b * BCAP;
    int cv = gcursor[b];
    if (cv > BCAP) cv = BCAP;
    if (b == 0) {  // dummy rows (read later by the gather kernels)
        if (t < 128) h[(size_t)n * 128 + t] = 0;
        if (t < 16) g[(size_t)n * 16 + t] = (_Float16)0.f;
        if (t == 0) dinv[n] = 1.f;
    }
    for (int i = t; i < (1 << BSH); i += 256) { ldeg[i] = 0; cur[i] = 0; }
    __syncthreads();
    // pass 1: per-node histogram (coalesced binned reads)
    for (int i = t; i < cv; i += 256)
        atomicAdd(&ldeg[binned[st + i] >> 17], 1);
    __syncthreads();
    // clamped exclusive prefix over 512 nodes (2/thread + H-S scan)
    int c0 = min(ldeg[2 * t], ELLW);
    int c1 = min(ldeg[2 * t + 1], ELLW);
    psum[t] = c0 + c1;
    __syncthreads();
    for (int o = 1; o < 256; o <<= 1) {
        int v = 0;
        if (t >= o) v = psum[t - o];
        __syncthreads();
        psum[t] += v;
        __syncthreads();
    }
    int base = psum[t] - (c0 + c1);
    off[2 * t] = base;
    off[2 * t + 1] = base + c0;
    __syncthreads();
    // pass 2: scatter into sorted LDS (clamped; sum of clamps <= cv <= BCAP)
    for (int i = t; i < cv; i += 256) {
        int v = binned[st + i];
        int dl = v >> 17;
        int r = atomicAdd(&cur[dl], 1);
        if (r < ELLW) sorted[off[dl] + r] = v & 0x1FFFF;
    }
    __syncthreads();
    // linear col write: int4, fully coalesced; pad with dummy node n
    const int nn = min(1 << BSH, n - node0);
    const int totv = nn * (ELLW / 4);
    int* colb = col + (size_t)node0 * ELLW;
    for (int idx = t; idx < totv; idx += 256) {
        int i = idx / (ELLW / 4);
        int q = (idx - i * (ELLW / 4)) * 4;
        int dc = min(ldeg[i], ELLW);
        int o = off[i];
        i32x4 v;
#pragma unroll
        for (int j = 0; j < 4; ++j)
            v[j] = (q + j < dc) ? sorted[o + q + j] : n;
        *(i32x4*)(colb + (size_t)i * ELLW + q) = v;
    }
    // deg + dinv (coalesced)
    for (int i = t; i < (1 << BSH); i += 256) {
        int node = node0 + i;
        if (node < n) {
            int dgv = ldeg[i];
            deg[node] = dgv;
            dinv[node] = rsqrtf((float)(min(dgv, ELLW) + 1));
        }
    }
}

// ---- K3: fused gather1 + relu + (128->16 matvec) + scale. g stored fp16 ----
__global__ __launch_bounds__(256, 2) void k_gather1f(
        const unsigned short* __restrict__ h, const int* __restrict__ deg,
        const float* __restrict__ dinv, const int* __restrict__ col,
        const float* __restrict__ b1, const float* __restrict__ W2,
        _Float16* __restrict__ g, int n) {
    const int t = threadIdx.x;
    const int lane = t & 15;
    const int d = blockIdx.x * 16 + (t >> 4);
    if (d >= n) return;
    int dg = deg[d];
    if (dg > ELLW) dg = ELLW;
    const float dd = dinv[d];
    const int kend = (dg + 7) & ~7;
    const int* ecol = col + (size_t)d * ELLW;

    float aA[8], aB[8];
    {   // self row: dinv[d] * h[d]
        short8 u = *(const short8*)(h + (size_t)d * 128 + lane * 8);
#pragma unroll
        for (int j = 0; j < 8; ++j) {
            aA[j] = dd * bf2f((unsigned short)u[j]);
            aB[j] = 0.f;
        }
    }
    for (int k = 0; k < kend; k += 8) {  // padded: full batches of 8
        int4 c0 = *(const int4*)(ecol + k);
        int4 c1 = *(const int4*)(ecol + k + 4);
        float e0 = dinv[c0.x], e1 = dinv[c0.y], e2 = dinv[c0.z], e3 = dinv[c0.w];
        float e4 = dinv[c1.x], e5 = dinv[c1.y], e6 = dinv[c1.z], e7 = dinv[c1.w];
        short8 u0 = *(const short8*)(h + (size_t)c0.x * 128 + lane * 8);
        short8 u1 = *(const short8*)(h + (size_t)c0.y * 128 + lane * 8);
        short8 u2 = *(const short8*)(h + (size_t)c0.z * 128 + lane * 8);
        short8 u3 = *(const short8*)(h + (size_t)c0.w * 128 + lane * 8);
        short8 u4 = *(const short8*)(h + (size_t)c1.x * 128 + lane * 8);
        short8 u5 = *(const short8*)(h + (size_t)c1.y * 128 + lane * 8);
        short8 u6 = *(const short8*)(h + (size_t)c1.z * 128 + lane * 8);
        short8 u7 = *(const short8*)(h + (size_t)c1.w * 128 + lane * 8);
#pragma unroll
        for (int j = 0; j < 8; ++j) {
            aA[j] = fmaf(bf2f((unsigned short)u0[j]), e0, aA[j]);
            aB[j] = fmaf(bf2f((unsigned short)u1[j]), e1, aB[j]);
            aA[j] = fmaf(bf2f((unsigned short)u2[j]), e2, aA[j]);
            aB[j] = fmaf(bf2f((unsigned short)u3[j]), e3, aB[j]);
            aA[j] = fmaf(bf2f((unsigned short)u4[j]), e4, aA[j]);
            aB[j] = fmaf(bf2f((unsigned short)u5[j]), e5, aB[j]);
            aA[j] = fmaf(bf2f((unsigned short)u6[j]), e6, aA[j]);
            aB[j] = fmaf(bf2f((unsigned short)u7[j]), e7, aB[j]);
        }
    }
    float y[8];
    const float* b1p = b1 + lane * 8;
#pragma unroll
    for (int j = 0; j < 8; ++j)
        y[j] = fmaxf(fmaf(aA[j] + aB[j], dd, b1p[j]), 0.f);
    const float4* w2v = (const float4*)(W2 + lane * 8 * 16);
    float4 z0 = make_float4(0.f, 0.f, 0.f, 0.f);
    float4 z1 = z0, z2 = z0, z3 = z0;
#pragma unroll
    for (int j = 0; j < 8; ++j) {
        float4 w0 = w2v[j * 4 + 0], w1 = w2v[j * 4 + 1];
        float4 w2 = w2v[j * 4 + 2], w3 = w2v[j * 4 + 3];
        float yj = y[j];
        z0.x = fmaf(yj, w0.x, z0.x); z0.y = fmaf(yj, w0.y, z0.y);
        z0.z = fmaf(yj, w0.z, z0.z); z0.w = fmaf(yj, w0.w, z0.w);
        z1.x = fmaf(yj, w1.x, z1.x); z1.y = fmaf(yj, w1.y, z1.y);
        z1.z = fmaf(yj, w1.z, z1.z); z1.w = fmaf(yj, w1.w, z1.w);
        z2.x = fmaf(yj, w2.x, z2.x); z2.y = fmaf(yj, w2.y, z2.y);
        z2.z = fmaf(yj, w2.z, z2.z); z2.w = fmaf(yj, w2.w, z2.w);
        z3.x = fmaf(yj, w3.x, z3.x); z3.y = fmaf(yj, w3.y, z3.y);
        z3.z = fmaf(yj, w3.z, z3.z); z3.w = fmaf(yj, w3.w, z3.w);
    }
#pragma unroll
    for (int mm = 1; mm < 16; mm <<= 1) {
        z0.x += __shfl_xor(z0.x, mm); z0.y += __shfl_xor(z0.y, mm);
        z0.z += __shfl_xor(z0.z, mm); z0.w += __shfl_xor(z0.w, mm);
        z1.x += __shfl_xor(z1.x, mm); z1.y += __shfl_xor(z1.y, mm);
        z1.z += __shfl_xor(z1.z, mm); z1.w += __shfl_xor(z1.w, mm);
        z2.x += __shfl_xor(z2.x, mm); z2.y += __shfl_xor(z2.y, mm);
        z2.z += __shfl_xor(z2.z, mm); z2.w += __shfl_xor(z2.w, mm);
        z3.x += __shfl_xor(z3.x, mm); z3.y += __shfl_xor(z3.y, mm);
        z3.z += __shfl_xor(z3.z, mm); z3.w += __shfl_xor(z3.w, mm);
    }
    if (lane < 4) {
        float4 z = (lane == 0) ? z0 : (lane == 1) ? z1 : (lane == 2) ? z2 : z3;
        f16x4 zz;
        zz[0] = (_Float16)(z.x * dd); zz[1] = (_Float16)(z.y * dd);
        zz[2] = (_Float16)(z.z * dd); zz[3] = (_Float16)(z.w * dd);
        *(f16x4*)(g + (size_t)d * 16 + lane * 4) = zz;  // 8B store, 32B row
    }
}

// ---- K4: gather2, 2 lanes/node f16x8 (16B) loads + bias + log_softmax ----
__global__ void k_gather2(const _Float16* __restrict__ g, const int* __restrict__ deg,
                          const int* __restrict__ col, const float* __restrict__ b2,
                          float* __restrict__ out, int n) {
    const int t = threadIdx.x;
    const int d = blockIdx.x * 128 + (t >> 1);
    if (d >= n) return;
    const int l = t & 1;
    int dg = deg[d];
    if (dg > ELLW) dg = ELLW;
    const float dd = rsqrtf((float)(dg + 1));
    const int kend = (dg + 7) & ~7;
    const int* ecol = col + (size_t)d * ELLW;
    const _Float16* gl = g + l * 8;

    float aA[8], aB[8];
    {   // self
        f16x8 s = *(const f16x8*)(gl + (size_t)d * 16);
#pragma unroll
        for (int j = 0; j < 8; ++j) { aA[j] = (float)s[j]; aB[j] = 0.f; }
    }
    for (int k = 0; k < kend; k += 8) {
        int4 c0 = *(const int4*)(ecol + k);
        int4 c1 = *(const int4*)(ecol + k + 4);
        f16x8 u0 = *(const f16x8*)(gl + (size_t)c0.x * 16);
        f16x8 u1 = *(const f16x8*)(gl + (size_t)c0.y * 16);
        f16x8 u2 = *(const f16x8*)(gl + (size_t)c0.z * 16);
        f16x8 u3 = *(const f16x8*)(gl + (size_t)c0.w * 16);
        f16x8 u4 = *(const f16x8*)(gl + (size_t)c1.x * 16);
        f16x8 u5 = *(const f16x8*)(gl + (size_t)c1.y * 16);
        f16x8 u6 = *(const f16x8*)(gl + (size_t)c1.z * 16);
        f16x8 u7 = *(const f16x8*)(gl + (size_t)c1.w * 16);
#pragma unroll
        for (int j = 0; j < 8; ++j) {
            aA[j] += (float)u0[j] + (float)u2[j] + (float)u4[j] + (float)u6[j];
            aB[j] += (float)u1[j] + (float)u3[j] + (float)u5[j] + (float)u7[j];
        }
    }
    float acc[8];
    const float* b2p = b2 + l * 8;
#pragma unroll
    for (int j = 0; j < 8; ++j) acc[j] = fmaf(aA[j] + aB[j], dd, b2p[j]);
    f32x4 o0 = {acc[0], acc[1], acc[2], acc[3]};
    f32x4 o1 = {acc[4], acc[5], acc[6], acc[7]};
    *(f32x4*)(out + (size_t)d * 16 + l * 8) = o0;
    *(f32x4*)(out + (size_t)d * 16 + l * 8 + 4) = o1;
    float m = acc[0];
#pragma unroll
    for (int j = 1; j < 8; ++j) m = fmaxf(m, acc[j]);
    m = fmaxf(m, __shfl_xor(m, 1));  // partner lane shares node (d = t>>1)
    float e = 0.f;
#pragma unroll
    for (int j = 0; j < 8; ++j) e += expf(acc[j] - m);
    e += __shfl_xor(e, 1);
    float ls = m + logf(e);
    f32x4 p0, p1;
#pragma unroll
    for (int j = 0; j < 4; ++j) { p0[j] = acc[j] - ls; p1[j] = acc[j + 4] - ls; }
    float* ob = out + (size_t)n * 16 + (size_t)d * 16 + l * 8;
    *(f32x4*)(ob) = p0;
    *(f32x4*)(ob + 4) = p1;
}

static inline size_t align256(size_t v) { return (v + 255) & ~(size_t)255; }

extern "C" void kernel_launch(void* const* d_in, const int* in_sizes, int n_in,
                              void* d_out, int out_size, void* d_ws, size_t ws_size,
                              hipStream_t stream) {
    const float* x  = (const float*)d_in[0];
    const int*   ei = (const int*)d_in[1];
    const float* W1 = (const float*)d_in[2];
    const float* b1 = (const float*)d_in[3];
    const float* W2 = (const float*)d_in[4];
    const float* b2 = (const float*)d_in[5];
    float* out = (float*)d_out;

    const int n = in_sizes[0] / 128;  // 100000
    const int E = in_sizes[1] / 2;    // 1600000
    const int* src = ei;
    const int* dst = ei + E;
    const int NEB = (E + EPB - 1) / EPB;            // 98
    const int NBUCK = (n + (1 << BSH) - 1) >> BSH;  // 196 (<= MAXBK)

    // workspace layout, 256B-aligned (~66.1 MB)
    char* base = (char*)d_ws;
    size_t off = 0;
    int* deg = (int*)(base + off); off = align256(off + (size_t)n * 4);
    float* dinv = (float*)(base + off); off = align256(off + ((size_t)n + 1) * 4);
    int* col = (int*)(base + off); off = align256(off + (size_t)n * ELLW * 4);
    unsigned short* h = (unsigned short*)(base + off); off = align256(off + ((size_t)n + 1) * 128 * 2);
    _Float16* g = (_Float16*)(base + off); off = align256(off + ((size_t)n + 1) * 16 * 2);
    int* gcursor = (int*)(base + off); off = align256(off + (size_t)MAXBK * 4);
    int* binned = (int*)(base + off); off = align256(off + (size_t)NBUCK * BCAP * 4);

    // M0: zero the per-bucket cursors (replaces prep kernel)
    hipMemsetAsync(gcursor, 0, (size_t)MAXBK * 4, stream);
    // K1: bin (fixed-region agg-atomic) ++ gemm1 (wt built per-block in LDS)
    k_bin_gemm<<<NEB + (n + 63) / 64, 256, 0, stream>>>(
        src, dst, E, gcursor, binned, NBUCK, NEB, x, W1, h, n);
    // K2: ell (counting sort per bucket; block 0 writes dummy rows)
    k_ell<<<NBUCK, 256, 0, stream>>>(binned, gcursor, deg, dinv, col, h, g, n);
    // K3: layer-1 fused gather + relu + matvec
    k_gather1f<<<(n + 15) / 16, 256, 0, stream>>>(h, deg, dinv, col, b1, W2, g, n);
    // K4: layer-2 aggregation + bias + log_softmax
    k_gather2<<<(n + 127) / 128, 256, 0, stream>>>(g, deg, col, b2, out, n);
}